// Round 12
// baseline (1743.591 us; speedup 1.0000x reference)
//
#include <hip/hip_runtime.h>
#include <hip/hip_bf16.h>
#include <cstdint>
#include <cstddef>

#define PI_F 3.14159265358979323846f
#define TWO_PI_F 6.28318530717958647692f

typedef __bf16 bf16x8 __attribute__((ext_vector_type(8)));
typedef __bf16 bf16x4 __attribute__((ext_vector_type(4)));
typedef float  f32x4  __attribute__((ext_vector_type(4)));

__device__ __forceinline__ __bf16 to_bf16(float f) { return (__bf16)f; }

// global -> LDS async copy, 16B per lane; LDS dest = wave-uniform base + lane*16
#define GLD_LDS16(gsrc, ldst)                                            \
  __builtin_amdgcn_global_load_lds(                                      \
      (const __attribute__((address_space(1))) void*)(gsrc),             \
      (__attribute__((address_space(3))) void*)(ldst), 16, 0, 0)

// ---------------------------------------------------------------------------
// 4-layer parameter chunk (48 VGPRs) — keeps the fused kernel under the
// 128-reg cap of __launch_bounds__(256,4). (R8's spill: 2x P8 = 192 regs.)
// ---------------------------------------------------------------------------
struct P4 {
  float4 qa[4];   // pair 2*lane   : (ec_re, ec_im, es_re, es_im)
  float4 qb[4];   // pair 2*lane+1
  float4 cc[4];   // (c_a, s_a, c_b, s_b)
};

__device__ __forceinline__ void loadP4(P4& P, int chunk, int lane,
    const float4* __restrict__ t4, const float2* __restrict__ t2) {
#pragma unroll
  for (int k = 0; k < 4; ++k) {
    int idx = (chunk * 4 + k) * 128 + 2 * lane;
    P.qa[k] = t4[idx];
    P.qb[k] = t4[idx + 1];
    P.cc[k] = *(const float4*)&t2[idx];   // idx even -> 16B aligned
  }
}

__device__ __forceinline__ void layer_step(bool odd, int lane,
    float4 qa, float4 qb, float4 cc,
    float& vre0, float& vim0, float& vre1, float& vim1,
    float& vre2, float& vim2, float& vre3, float& vim3) {
  if (!odd) {
    float nr0 = qa.x * vre0 - qa.y * vim0 + qa.z * vre1 - qa.w * vim1;
    float ni0 = qa.x * vim0 + qa.y * vre0 + qa.z * vim1 + qa.w * vre1;
    float nr1 = cc.x * vre1 - cc.y * vre0;
    float ni1 = cc.x * vim1 - cc.y * vim0;
    float nr2 = qb.x * vre2 - qb.y * vim2 + qb.z * vre3 - qb.w * vim3;
    float ni2 = qb.x * vim2 + qb.y * vre2 + qb.z * vim3 + qb.w * vre3;
    float nr3 = cc.z * vre3 - cc.w * vre2;
    float ni3 = cc.z * vim3 - cc.w * vim2;
    vre0 = nr0; vim0 = ni0; vre1 = nr1; vim1 = ni1;
    vre2 = nr2; vim2 = ni2; vre3 = nr3; vim3 = ni3;
  } else {
    int nxt = (lane + 1) & 63, prv = (lane + 63) & 63;
    float xre = __shfl(vre0, nxt, 64);
    float xim = __shfl(vim0, nxt, 64);
    float pre = __shfl(vre3, prv, 64);
    float pim = __shfl(vim3, prv, 64);
    float cp  = __shfl(cc.z, prv, 64);
    float sp  = __shfl(cc.w, prv, 64);
    float nr1 = qa.x * vre1 - qa.y * vim1 + qa.z * vre2 - qa.w * vim2;
    float ni1 = qa.x * vim1 + qa.y * vre1 + qa.z * vim2 + qa.w * vre2;
    float nr2 = cc.x * vre2 - cc.y * vre1;
    float ni2 = cc.x * vim2 - cc.y * vim1;
    float nr3 = qb.x * vre3 - qb.y * vim3 + qb.z * xre - qb.w * xim;
    float ni3 = qb.x * vim3 + qb.y * vre3 + qb.z * xim + qb.w * xre;
    float nr0 = cp * vre0 - sp * pre;
    float ni0 = cp * vim0 - sp * pim;
    vre0 = nr0; vim0 = ni0; vre1 = nr1; vim1 = ni1;
    vre2 = nr2; vim2 = ni2; vre3 = nr3; vim3 = ni3;
  }
}

// ---------------------------------------------------------------------------
// FUSED kernel, take 2. Grid 1024 x 256, launch_bounds(256,4), LDS 32KB:
// 16 waves/CU @ <=128 VGPR and 4x32KB LDS -> ALL 1024 blocks resident
// simultaneously; flag spins cannot deadlock under any dispatch order.
//   blocks 16..143: compute params table (t4/t2) -> flag1 (128)
//   blocks 0..15  : spin flag1, build T rows (P4 dbuf) -> Tb2, flag2 (16)
//   all blocks    : prefetch tile-0 x burst BEFORE spinning flag2 (overlap),
//                   then B->LDS stage, then the R4-proven 2-tile mm body.
// Plain (non-nt) loads/stores: R4 (83.3) beat R9-nt (90.0).
// ---------------------------------------------------------------------------
__global__ __launch_bounds__(256, 4) void olk_fused(
    const float* __restrict__ x, const float* __restrict__ theta,
    const float* __restrict__ phi, const float* __restrict__ outph,
    float* __restrict__ out, unsigned* __restrict__ flag1,
    unsigned* __restrict__ flag2,
    float4* __restrict__ t4, float2* __restrict__ t2,
    __bf16* __restrict__ Tb2) {
  __shared__ __bf16 Bl[32 * 512];   // 32 KB: 32 frag-sets x 64 lanes x 8 bf16
  int tid = threadIdx.x, lane = tid & 63, w = tid >> 6;
  int l15 = lane & 15, lg = lane >> 4;
  int bid = blockIdx.x;

  int mt0 = (bid * 4 + w) * 2;      // this wave's 2 m-tiles (1024*4*2 = 8192)

  f32x4 L[16];
  bf16x8 a[8];
  f32x4 acc[4];

#define ISSUE(t)                                                          \
  do {                                                                    \
    const float* xr_ = x + ((size_t)((t) * 16 + l15) << 8) + 4 * lg;      \
    __builtin_amdgcn_sched_barrier(0);                                    \
    _Pragma("unroll")                                                     \
    for (int ks = 0; ks < 8; ++ks) {                                      \
      L[2 * ks]     = *(const f32x4*)(xr_ + ks * 32);                     \
      L[2 * ks + 1] = *(const f32x4*)(xr_ + ks * 32 + 16);                \
    }                                                                     \
    __builtin_amdgcn_sched_barrier(0);                                    \
  } while (0)

#define CVT()                                                             \
  do {                                                                    \
    _Pragma("unroll")                                                     \
    for (int ks = 0; ks < 8; ++ks) {                                      \
      f32x4 lo_ = L[2 * ks], hi_ = L[2 * ks + 1];                         \
      bf16x8 v_;                                                          \
      v_[0] = to_bf16(lo_.x); v_[1] = to_bf16(lo_.y);                     \
      v_[2] = to_bf16(lo_.z); v_[3] = to_bf16(lo_.w);                     \
      v_[4] = to_bf16(hi_.x); v_[5] = to_bf16(hi_.y);                     \
      v_[6] = to_bf16(hi_.z); v_[7] = to_bf16(hi_.w);                     \
      a[ks] = v_;                                                         \
    }                                                                     \
  } while (0)

#define MFMA(bb)                                                          \
  do {                                                                    \
    _Pragma("unroll")                                                     \
    for (int nt = 0; nt < 4; ++nt) acc[nt] = (f32x4){0.f, 0.f, 0.f, 0.f}; \
    _Pragma("unroll")                                                     \
    for (int ks = 0; ks < 8; ++ks)                                        \
      _Pragma("unroll")                                                   \
      for (int nt = 0; nt < 4; ++nt) {                                    \
        bf16x8 bv_ = *(const bf16x8*)&Bl[(bb) + (ks * 4 + nt) * 512 + lane * 8]; \
        acc[nt] = __builtin_amdgcn_mfma_f32_16x16x32_bf16(a[ks], bv_, acc[nt], 0, 0, 0); \
      }                                                                   \
  } while (0)

#define STORE(t)                                                          \
  do {                                                                    \
    float* ob_ = out + ((size_t)(t) * 16) * 64 + l15;                     \
    _Pragma("unroll")                                                     \
    for (int r = 0; r < 4; ++r)                                           \
      _Pragma("unroll")                                                   \
      for (int nt = 0; nt < 4; ++nt)                                      \
        ob_[(4 * lg + r) * 64 + nt * 16] = acc[nt][r];                    \
  } while (0)

  if (bid >= 16 && bid < 144) {
    // ---- params phase: idx = (bid-16)*256 + tid, 128 blocks cover 32768 ----
    int idx = (bid - 16) * 256 + tid;
    float t = fmodf(theta[idx], PI_F);
    float p = phi[idx];
    if (t > 0.5f * PI_F) { t = PI_F - t; p += PI_F; }
    p = fmodf(p, TWO_PI_F);
    float c  = cosf(t), s  = sinf(t);
    float cp = cosf(p), sp = sinf(p);
    t4[idx] = make_float4(cp * c, sp * c, cp * s, sp * s);
    t2[idx] = make_float2(c, s);
    __threadfence();
    __syncthreads();
    if (tid == 0)
      __hip_atomic_fetch_add(flag1, 1u, __ATOMIC_RELEASE, __HIP_MEMORY_SCOPE_AGENT);
    ISSUE(mt0);    // prefetch under the build
  } else if (bid < 16) {
    // ---- build phase: row r = bid*4 + w ----
    if (tid == 0) {
      while (__hip_atomic_load(flag1, __ATOMIC_ACQUIRE, __HIP_MEMORY_SCOPE_AGENT) != 128u)
        __builtin_amdgcn_s_sleep(8);
    }
    __syncthreads();

    int r = bid * 4 + w;
    int c0 = lane * 4;
    float vre0 = (c0 + 0 == r) ? 1.f : 0.f, vim0 = 0.f;
    float vre1 = (c0 + 1 == r) ? 1.f : 0.f, vim1 = 0.f;
    float vre2 = (c0 + 2 == r) ? 1.f : 0.f, vim2 = 0.f;
    float vre3 = (c0 + 3 == r) ? 1.f : 0.f, vim3 = 0.f;

    P4 A, B;
    loadP4(A, 63, lane, t4, t2);               // layers 255..252
#pragma unroll 1
    for (int it = 0; it < 32; ++it) {
      int cA = 63 - 2 * it, cB = cA - 1;
      loadP4(B, cB, lane, t4, t2);
#pragma unroll
      for (int k = 3; k >= 0; --k)             // layer = cA*4+k descending
        layer_step((k & 1) != 0, lane, A.qa[k], A.qb[k], A.cc[k],
                   vre0, vim0, vre1, vim1, vre2, vim2, vre3, vim3);
      if (it < 31)
        loadP4(A, cB - 1, lane, t4, t2);
#pragma unroll
      for (int k = 3; k >= 0; --k)
        layer_step((k & 1) != 0, lane, B.qa[k], B.qb[k], B.cc[k],
                   vre0, vim0, vre1, vim1, vre2, vim2, vre3, vim3);
    }

    float oph = outph[r];
    float co = cosf(oph), so = sinf(oph);
    bf16x4 o;
    o[0] = to_bf16(co * vre0 - so * vim0);
    o[1] = to_bf16(co * vre1 - so * vim1);
    o[2] = to_bf16(co * vre2 - so * vim2);
    o[3] = to_bf16(co * vre3 - so * vim3);
    int ksb = lane >> 3, sub = lane & 7;
    int pos = ksb * 32 + (sub & 3) * 8 + (sub >> 2) * 4;
    *(bf16x4*)(Tb2 + r * 256 + pos) = o;       // frag-ordered 16B B-frags

    __threadfence();
    __syncthreads();
    if (tid == 0)
      __hip_atomic_fetch_add(flag2, 1u, __ATOMIC_RELEASE, __HIP_MEMORY_SCOPE_AGENT);
    ISSUE(mt0);
  } else {
    // ---- plain consumer: prefetch tile-0 under params+build ----
    ISSUE(mt0);
  }

  // ---- wait until all 16 build blocks published Tb2 ----
  if (tid == 0) {
    while (__hip_atomic_load(flag2, __ATOMIC_ACQUIRE, __HIP_MEMORY_SCOPE_AGENT) != 16u)
      __builtin_amdgcn_s_sleep(16);
  }
  __syncthreads();

  // ---- stage B -> LDS (frag-set idx = ks*4+nt; wave stages w*8+j) ----
#pragma unroll
  for (int j = 0; j < 8; ++j) {
    int idx = w * 8 + j;
    int ks = idx >> 2, nt = idx & 3;
    const __bf16* src = Tb2 + (nt * 16 + l15) * 256 + ks * 32 + lg * 8;
    GLD_LDS16(src, &Bl[idx * 512]);
  }
  __syncthreads();   // drains vmcnt: B in LDS + tile-0 burst in L

  unsigned bb = 0;
  asm volatile("" : "+v"(bb));   // opaque 0: keep B reads in LDS (no LICM/CSE)

  // ---- mm body (R4-proven): 2 tiles, depth-1 pipeline, no barriers ----
  CVT();
  ISSUE(mt0 + 1);
  MFMA(bb);
  STORE(mt0);
  CVT();
  MFMA(bb);
  STORE(mt0 + 1);

#undef ISSUE
#undef CVT
#undef MFMA
#undef STORE
}

// ---------------------------------------------------------------------------
extern "C" void kernel_launch(void* const* d_in, const int* in_sizes, int n_in,
                              void* d_out, int out_size, void* d_ws, size_t ws_size,
                              hipStream_t stream) {
  const float* x     = (const float*)d_in[0];
  const float* theta = (const float*)d_in[1];
  const float* phi   = (const float*)d_in[2];
  const float* outph = (const float*)d_in[3];
  float* out = (float*)d_out;

  char* ws = (char*)d_ws;
  unsigned* flag1 = (unsigned*)ws;                    // 4 B
  unsigned* flag2 = (unsigned*)(ws + 4);              // 4 B
  float4* t4  = (float4*)(ws + 4096);                 // 512 KB
  float2* t2  = (float2*)(ws + 4096 + 512 * 1024);    // 256 KB
  __bf16* Tb2 = (__bf16*)(ws + 4096 + 768 * 1024);    // 32 KB frag-ordered T

  (void)hipMemsetAsync(ws, 0, 8, stream);             // reset flags (graph-safe)
  olk_fused<<<1024, 256, 0, stream>>>(x, theta, phi, outph, out,
                                      flag1, flag2, t4, t2, Tb2);
}